// Round 1
// baseline (80.503 us; speedup 1.0000x reference)
//
#include <hip/hip_runtime.h>

// Bipolar LIF forward.
// in : [B=8, T=32, N=1024, F=128] f32
// out: [B, T, N, 2F]  (pos spikes in [0:F), neg spikes in [F:2F))
//
// Recurrence per channel (b,n,f), t = 0..T-1:
//   V = alpha*V + x          (separate mul/add rounding — match XLA/np)
//   pos = (V >= 1.0), neg = (V <= -1.0)
//   V = V - (pos*1.0 - neg*(-1.0)) = V - (pos + neg)   (single rounded sub)
//
// One thread owns 4 consecutive f (float4) of one (b,n) row and loops over T.
// Pure streaming: 134 MB read + 268 MB write -> HBM-bound, ~64 us roofline.

constexpr int B_ = 8, T_ = 32, N_ = 1024, F_ = 128;
constexpr int FV = F_ / 4;          // 32 float4 per (b,t,n) input row
constexpr int CH = B_ * N_ * FV;    // 262144 threads

__global__ __launch_bounds__(256)
void lif_fwd_kernel(const float4* __restrict__ in, float4* __restrict__ out) {
    int g = blockIdx.x * 256 + threadIdx.x;
    if (g >= CH) return;

    const int fv = g & (FV - 1);        // float4 index within F
    const int bn = g >> 5;              // b*N + n
    const int b  = bn >> 10;            // / N
    const int n  = bn & (N_ - 1);

    // fp32 correctly-rounded exp(-1/20); decimal literal rounds to it exactly.
    const float alpha = 0.95122942450071400910f;

    int in_idx  = ((b * T_) * N_ + n) * FV + fv;        // float4 index
    int out_idx = ((b * T_) * N_ + n) * (2 * FV) + fv;  // float4 index
    const int in_stride  = N_ * FV;        // per-t stride (float4)
    const int out_stride = N_ * 2 * FV;

    float v0 = 0.0f, v1 = 0.0f, v2 = 0.0f, v3 = 0.0f;

    #pragma unroll
    for (int t = 0; t < T_; ++t) {
        const float4 x = in[in_idx];
        in_idx += in_stride;

        // V = alpha*V + x with separate rounding (never FMA-contracted).
        v0 = __fadd_rn(__fmul_rn(alpha, v0), x.x);
        v1 = __fadd_rn(__fmul_rn(alpha, v1), x.y);
        v2 = __fadd_rn(__fmul_rn(alpha, v2), x.z);
        v3 = __fadd_rn(__fmul_rn(alpha, v3), x.w);

        float4 pos, neg;
        pos.x = (v0 >=  1.0f) ? 1.0f : 0.0f;
        pos.y = (v1 >=  1.0f) ? 1.0f : 0.0f;
        pos.z = (v2 >=  1.0f) ? 1.0f : 0.0f;
        pos.w = (v3 >=  1.0f) ? 1.0f : 0.0f;
        neg.x = (v0 <= -1.0f) ? 1.0f : 0.0f;
        neg.y = (v1 <= -1.0f) ? 1.0f : 0.0f;
        neg.z = (v2 <= -1.0f) ? 1.0f : 0.0f;
        neg.w = (v3 <= -1.0f) ? 1.0f : 0.0f;

        // Reset: V -= (pos + neg); sum is exactly 0 or 1 (mutually exclusive),
        // so this is the same single rounded subtract as the reference.
        v0 = __fsub_rn(v0, pos.x + neg.x);
        v1 = __fsub_rn(v1, pos.y + neg.y);
        v2 = __fsub_rn(v2, pos.z + neg.z);
        v3 = __fsub_rn(v3, pos.w + neg.w);

        out[out_idx]      = pos;   // [b,t,n, 0:F)
        out[out_idx + FV] = neg;   // [b,t,n, F:2F)
        out_idx += out_stride;
    }
}

extern "C" void kernel_launch(void* const* d_in, const int* in_sizes, int n_in,
                              void* d_out, int out_size, void* d_ws, size_t ws_size,
                              hipStream_t stream) {
    const float4* in  = (const float4*)d_in[0];
    float4*       out = (float4*)d_out;
    const int blocks = CH / 256;   // 1024
    lif_fwd_kernel<<<blocks, 256, 0, stream>>>(in, out);
}

// Round 3
// 74.350 us; speedup vs baseline: 1.0828x; 1.0828x over previous
//
#include <hip/hip_runtime.h>

// Bipolar LIF forward.
// in : [B=8, T=32, N=1024, F=128] f32
// out: [B, T, N, 2F]  (pos spikes in [0:F), neg spikes in [F:2F))
//
// Recurrence per channel (b,n,f), t = 0..T-1:
//   V = alpha*V + x          (separate mul/add rounding — match XLA/np)
//   pos = (V >= 1.0), neg = (V <= -1.0)
//   V = V - (pos + neg)      (single rounded sub; pos/neg mutually exclusive)
//
// One thread owns 4 consecutive f (float4) of one (b,n) row and loops over T.
// Pure streaming: 134 MB read + 268 MB write -> HBM-bound.
// R1: 80.5 us (5.0 TB/s effective). R3: non-temporal hints via native clang
// vector type (HIP_vector_type structs are rejected by the builtin).

constexpr int B_ = 8, T_ = 32, N_ = 1024, F_ = 128;
constexpr int FV = F_ / 4;          // 32 float4 per (b,t,n) input row
constexpr int CH = B_ * N_ * FV;    // 262144 threads

typedef float vf4 __attribute__((ext_vector_type(4)));

__global__ __launch_bounds__(256)
void lif_fwd_kernel(const vf4* __restrict__ in, vf4* __restrict__ out) {
    int g = blockIdx.x * 256 + threadIdx.x;
    if (g >= CH) return;

    const int fv = g & (FV - 1);        // float4 index within F
    const int bn = g >> 5;              // b*N + n
    const int b  = bn >> 10;            // / N
    const int n  = bn & (N_ - 1);

    // fp32 correctly-rounded exp(-1/20); decimal literal rounds to it exactly.
    const float alpha = 0.95122942450071400910f;

    int in_idx  = ((b * T_) * N_ + n) * FV + fv;        // float4 index
    int out_idx = ((b * T_) * N_ + n) * (2 * FV) + fv;  // float4 index
    const int in_stride  = N_ * FV;        // per-t stride (float4)
    const int out_stride = N_ * 2 * FV;

    float v0 = 0.0f, v1 = 0.0f, v2 = 0.0f, v3 = 0.0f;

    #pragma unroll
    for (int t = 0; t < T_; ++t) {
        const vf4 x = __builtin_nontemporal_load(&in[in_idx]);
        in_idx += in_stride;

        // V = alpha*V + x with separate rounding (never FMA-contracted).
        v0 = __fadd_rn(__fmul_rn(alpha, v0), x.x);
        v1 = __fadd_rn(__fmul_rn(alpha, v1), x.y);
        v2 = __fadd_rn(__fmul_rn(alpha, v2), x.z);
        v3 = __fadd_rn(__fmul_rn(alpha, v3), x.w);

        vf4 pos, neg;
        pos.x = (v0 >=  1.0f) ? 1.0f : 0.0f;
        pos.y = (v1 >=  1.0f) ? 1.0f : 0.0f;
        pos.z = (v2 >=  1.0f) ? 1.0f : 0.0f;
        pos.w = (v3 >=  1.0f) ? 1.0f : 0.0f;
        neg.x = (v0 <= -1.0f) ? 1.0f : 0.0f;
        neg.y = (v1 <= -1.0f) ? 1.0f : 0.0f;
        neg.z = (v2 <= -1.0f) ? 1.0f : 0.0f;
        neg.w = (v3 <= -1.0f) ? 1.0f : 0.0f;

        // Reset: V -= (pos + neg); sum is exactly 0 or 1 (mutually exclusive),
        // so this is the same single rounded subtract as the reference.
        v0 = __fsub_rn(v0, pos.x + neg.x);
        v1 = __fsub_rn(v1, pos.y + neg.y);
        v2 = __fsub_rn(v2, pos.z + neg.z);
        v3 = __fsub_rn(v3, pos.w + neg.w);

        __builtin_nontemporal_store(pos, &out[out_idx]);       // [b,t,n, 0:F)
        __builtin_nontemporal_store(neg, &out[out_idx + FV]);  // [b,t,n, F:2F)
        out_idx += out_stride;
    }
}

extern "C" void kernel_launch(void* const* d_in, const int* in_sizes, int n_in,
                              void* d_out, int out_size, void* d_ws, size_t ws_size,
                              hipStream_t stream) {
    const vf4* in  = (const vf4*)d_in[0];
    vf4*       out = (vf4*)d_out;
    const int blocks = CH / 256;   // 1024
    lif_fwd_kernel<<<blocks, 256, 0, stream>>>(in, out);
}

// Round 4
// 70.765 us; speedup vs baseline: 1.1376x; 1.0507x over previous
//
#include <hip/hip_runtime.h>

// Bipolar LIF forward.
// in : [B=8, T=32, N=1024, F=128] f32
// out: [B, T, N, 2F]  (pos spikes in [0:F), neg spikes in [F:2F))
//
// Recurrence per channel (b,n,f), t = 0..T-1:
//   V = alpha*V + x          (separate mul/add rounding — match XLA/np)
//   pos = (V >= 1.0), neg = (V <= -1.0)
//   V = V - (pos + neg)      (single rounded sub; pos/neg mutually exclusive)
//
// Pure streaming: 134 MB read + 268 MB write -> HBM-bound.
// R1: float4/thread, 16 waves/CU           -> 80.5 us (5.0 TB/s)
// R3: + non-temporal load/store            -> 74.4 us (5.4 TB/s)
// R4: float2/thread -> 8192 waves = 32 waves/CU (full occupancy, TLP for
//     latency hiding); one wave == one (b,n) row: 512B load, 2x512B stores,
//     all contiguous per wave. __launch_bounds__(256,8) caps VGPR<=64.

constexpr int B_ = 8, T_ = 32, N_ = 1024, F_ = 128;
constexpr int FV = F_ / 2;          // 64 float2 per (b,t,n) input row
constexpr int CH = B_ * N_ * FV;    // 524288 threads

typedef float vf2 __attribute__((ext_vector_type(2)));

__global__ __launch_bounds__(256, 8)
void lif_fwd_kernel(const vf2* __restrict__ in, vf2* __restrict__ out) {
    int g = blockIdx.x * 256 + threadIdx.x;

    const int fv = g & (FV - 1);        // float2 index within F
    const int bn = g >> 6;              // b*N + n
    const int b  = bn >> 10;            // / N
    const int n  = bn & (N_ - 1);

    // fp32 correctly-rounded exp(-1/20); decimal literal rounds to it exactly.
    const float alpha = 0.95122942450071400910f;

    int in_idx  = ((b * T_) * N_ + n) * FV + fv;        // float2 index
    int out_idx = ((b * T_) * N_ + n) * (2 * FV) + fv;  // float2 index
    const int in_stride  = N_ * FV;        // per-t stride (float2)
    const int out_stride = N_ * 2 * FV;

    float v0 = 0.0f, v1 = 0.0f;

    #pragma unroll
    for (int t = 0; t < T_; ++t) {
        const vf2 x = __builtin_nontemporal_load(&in[in_idx]);
        in_idx += in_stride;

        // V = alpha*V + x with separate rounding (never FMA-contracted).
        v0 = __fadd_rn(__fmul_rn(alpha, v0), x.x);
        v1 = __fadd_rn(__fmul_rn(alpha, v1), x.y);

        vf2 pos, neg;
        pos.x = (v0 >=  1.0f) ? 1.0f : 0.0f;
        pos.y = (v1 >=  1.0f) ? 1.0f : 0.0f;
        neg.x = (v0 <= -1.0f) ? 1.0f : 0.0f;
        neg.y = (v1 <= -1.0f) ? 1.0f : 0.0f;

        // Reset: V -= (pos + neg); sum is exactly 0 or 1 (mutually exclusive),
        // so this is the same single rounded subtract as the reference.
        v0 = __fsub_rn(v0, pos.x + neg.x);
        v1 = __fsub_rn(v1, pos.y + neg.y);

        __builtin_nontemporal_store(pos, &out[out_idx]);       // [b,t,n, 0:F)
        __builtin_nontemporal_store(neg, &out[out_idx + FV]);  // [b,t,n, F:2F)
        out_idx += out_stride;
    }
}

extern "C" void kernel_launch(void* const* d_in, const int* in_sizes, int n_in,
                              void* d_out, int out_size, void* d_ws, size_t ws_size,
                              hipStream_t stream) {
    const vf2* in  = (const vf2*)d_in[0];
    vf2*       out = (vf2*)d_out;
    const int blocks = CH / 256;   // 2048
    lif_fwd_kernel<<<blocks, 256, 0, stream>>>(in, out);
}

// Round 5
// 70.640 us; speedup vs baseline: 1.1396x; 1.0018x over previous
//
#include <hip/hip_runtime.h>

// Bipolar LIF forward.
// in : [B=8, T=32, N=1024, F=128] f32
// out: [B, T, N, 2F]  (pos spikes in [0:F), neg spikes in [F:2F))
//
// Recurrence per channel (b,n,f), t = 0..T-1:
//   V = alpha*V + x          (separate mul/add rounding — match XLA/np)
//   pos = (V >= 1.0), neg = (V <= -1.0)
//   V = V - (pos + neg)      (single rounded sub; pos/neg mutually exclusive)
//
// Pure streaming: 134 MB read + 268 MB write -> HBM-bound.
// R1: float4/thread, 16 waves/CU           -> 80.5 us (5.0 TB/s)
// R3: + non-temporal load/store            -> 74.4 us (5.4 TB/s)
// R4: float2/thread, 32 waves/CU (full)    -> 70.8 us (5.7 TB/s)
// R5: explicit 2-deep load prefetch — guarantee load(t+1) issues before the
//     vmcnt-wait on load(t), so each wave always has a read in flight and the
//     store burst overlaps the next read's latency.

constexpr int B_ = 8, T_ = 32, N_ = 1024, F_ = 128;
constexpr int FV = F_ / 2;          // 64 float2 per (b,t,n) input row
constexpr int CH = B_ * N_ * FV;    // 524288 threads

typedef float vf2 __attribute__((ext_vector_type(2)));

__global__ __launch_bounds__(256, 8)
void lif_fwd_kernel(const vf2* __restrict__ in, vf2* __restrict__ out) {
    int g = blockIdx.x * 256 + threadIdx.x;

    const int fv = g & (FV - 1);        // float2 index within F
    const int bn = g >> 6;              // b*N + n
    const int b  = bn >> 10;            // / N
    const int n  = bn & (N_ - 1);

    // fp32 correctly-rounded exp(-1/20); decimal literal rounds to it exactly.
    const float alpha = 0.95122942450071400910f;

    int in_idx  = ((b * T_) * N_ + n) * FV + fv;        // float2 index
    int out_idx = ((b * T_) * N_ + n) * (2 * FV) + fv;  // float2 index
    const int in_stride  = N_ * FV;        // per-t stride (float2)
    const int out_stride = N_ * 2 * FV;

    float v0 = 0.0f, v1 = 0.0f;

    // Prime the pipeline: x for t=0 in flight before the loop.
    vf2 x = __builtin_nontemporal_load(&in[in_idx]);
    in_idx += in_stride;

    #pragma unroll
    for (int t = 0; t < T_; ++t) {
        // Issue next load BEFORE consuming x (keeps >=1 read in flight).
        vf2 xn;
        if (t < T_ - 1) {
            xn = __builtin_nontemporal_load(&in[in_idx]);
            in_idx += in_stride;
        }

        // V = alpha*V + x with separate rounding (never FMA-contracted).
        v0 = __fadd_rn(__fmul_rn(alpha, v0), x.x);
        v1 = __fadd_rn(__fmul_rn(alpha, v1), x.y);

        vf2 pos, neg;
        pos.x = (v0 >=  1.0f) ? 1.0f : 0.0f;
        pos.y = (v1 >=  1.0f) ? 1.0f : 0.0f;
        neg.x = (v0 <= -1.0f) ? 1.0f : 0.0f;
        neg.y = (v1 <= -1.0f) ? 1.0f : 0.0f;

        // Reset: V -= (pos + neg); sum is exactly 0 or 1 (mutually exclusive),
        // so this is the same single rounded subtract as the reference.
        v0 = __fsub_rn(v0, pos.x + neg.x);
        v1 = __fsub_rn(v1, pos.y + neg.y);

        __builtin_nontemporal_store(pos, &out[out_idx]);       // [b,t,n, 0:F)
        __builtin_nontemporal_store(neg, &out[out_idx + FV]);  // [b,t,n, F:2F)
        out_idx += out_stride;

        x = xn;
    }
}

extern "C" void kernel_launch(void* const* d_in, const int* in_sizes, int n_in,
                              void* d_out, int out_size, void* d_ws, size_t ws_size,
                              hipStream_t stream) {
    const vf2* in  = (const vf2*)d_in[0];
    vf2*       out = (vf2*)d_out;
    const int blocks = CH / 256;   // 2048
    lif_fwd_kernel<<<blocks, 256, 0, stream>>>(in, out);
}